// Round 11
// baseline (223.069 us; speedup 1.0000x reference)
//
#include <hip/hip_runtime.h>

// ---------------------------------------------------------------------------
// LSH attention, MI355X.  B=2, S=2048, E=1024, H=16, Dh=64, NB=64, NH=6.
// ALL inputs/outputs are FP32.
// R11: merged Q+V projection blocks.  A Q-tile [m0 tokens x n0 channels] and
// the V^T-tile [n0 channels x m0 tokens] consume the SAME x-tile; merging
// them into one 512-thread block stages 5 LDS arrays (80 KB: xh,xl,wqh,wql,
// wvh) instead of 6 across two 256-thread blocks, 10 glds16/wave instead of
// 12, and halves barrier sequences.  V computed transposed (A=wv frags,
// B=x frags) so both epilogue writes stay coalesced.  Same fragment/swizzle
// math, same per-output FLOP order -> bit-identical Q and V.  Grid 256 =
// 1 block/CU = 2 waves/SIMD (occupancy regime unchanged -- R2/R4/R9 proved
// raising it regresses).  XCD map kept: m-tile == blk (mod 8).
// attn: EXACT verified R8 (101.5us).  split/bucket: R5.
//   0) split_all: x -> xh+xl, Wq -> Wqh+Wql, Wv -> Wvh in ONE launch
//   1) gemm_qv: 256 blocks x 512 thr, 128x128 tile, BK=64, merged Q+V
//   2) bucket_kernel: bucket bits from hi+lo q; row |q|^2
//   3) attn_kernel: grid (32,16), 4 waves x 32 q-rows, K-tile 64
// ---------------------------------------------------------------------------

typedef short short8 __attribute__((ext_vector_type(8)));
typedef float f32x4 __attribute__((ext_vector_type(4)));
typedef unsigned short us4 __attribute__((ext_vector_type(4)));

__device__ __forceinline__ float bff(unsigned short h) {
    return __uint_as_float(((unsigned int)h) << 16);
}
__device__ __forceinline__ unsigned short f2bf(float f) {  // RNE, finite inputs
    unsigned int u = __float_as_uint(f);
    u += 0x7fffu + ((u >> 16) & 1u);
    return (unsigned short)(u >> 16);
}

__device__ __forceinline__ void glds16(const unsigned short* g, unsigned short* l) {
    __builtin_amdgcn_global_load_lds(
        (const __attribute__((address_space(1))) unsigned int*)g,
        (__attribute__((address_space(3))) unsigned int*)l, 16, 0, 0);
}

// ---------------------------------------------------------------------------
// Fused split: blk<4096 -> x (hi+lo); <5120 -> Wq (hi+lo); else Wv (hi).
// ---------------------------------------------------------------------------
__global__ __launch_bounds__(256) void split_all(
    const float* __restrict__ x, const float* __restrict__ Wq,
    const float* __restrict__ Wv,
    unsigned short* __restrict__ xh, unsigned short* __restrict__ xl,
    unsigned short* __restrict__ Wqh, unsigned short* __restrict__ Wql,
    unsigned short* __restrict__ Wvh)
{
    const int blk = blockIdx.x;
    const float* in;
    unsigned short *hi, *lo;
    int idx;
    if (blk < 4096) {
        idx = blk * 256 + threadIdx.x; in = x; hi = xh; lo = xl;
    } else if (blk < 5120) {
        idx = (blk - 4096) * 256 + threadIdx.x; in = Wq; hi = Wqh; lo = Wql;
    } else {
        idx = (blk - 5120) * 256 + threadIdx.x; in = Wv; hi = Wvh; lo = nullptr;
    }
    const float4 v = ((const float4*)in)[idx];
    us4 h;
    h.x = f2bf(v.x); h.y = f2bf(v.y); h.z = f2bf(v.z); h.w = f2bf(v.w);
    ((us4*)hi)[idx] = h;
    if (lo) {
        us4 l;
        l.x = f2bf(v.x - bff(h.x)); l.y = f2bf(v.y - bff(h.y));
        l.z = f2bf(v.z - bff(h.z)); l.w = f2bf(v.w - bff(h.w));
        ((us4*)lo)[idx] = l;
    }
}

// ---------------------------------------------------------------------------
// Merged Q+V projection GEMM.  256 blocks x 512 threads (8 waves).  Block
// (m0 token-tile, n0 channel-tile): Q[m0][n0] (3-term hi/lo) and
// V^T[n0][m0] (1-term) from one x-staging.  LDS 80 KB (5 arrays), BK=64.
// Wave w owns output cols w*16..w*16+15 (Q: channels; V^T: tokens).
// XCD-locality: m-tile%8 == blk%8.
// ---------------------------------------------------------------------------
__global__ __launch_bounds__(512, 2) void gemm_qv(
    const unsigned short* __restrict__ xh, const unsigned short* __restrict__ xl,
    const unsigned short* __restrict__ wqh, const unsigned short* __restrict__ wql,
    const unsigned short* __restrict__ wvh,
    const float* __restrict__ bq, const float* __restrict__ bv,
    unsigned short* __restrict__ Qb, unsigned short* __restrict__ Qlo,
    unsigned short* __restrict__ Vt)
{
    __shared__ unsigned short Ah[128 * 64], Al[128 * 64];
    __shared__ unsigned short Bh[128 * 64], Bl[128 * 64];
    __shared__ unsigned short Cv[128 * 64];

    const int tid = threadIdx.x;
    const int w = tid >> 6, lane = tid & 63;
    const int i = lane & 15, qd = lane >> 4;
    const int l8 = lane >> 3, j = lane & 7;
    const int blk = blockIdx.x;

    // XCD-locality remap: m-tile%8 == blk%8 (== XCD under round-robin)
    const int m0 = ((blk & 7) + 8 * ((blk >> 3) & 3)) * 128;  // token tile
    const int n0 = (blk >> 5) * 128;                          // channel tile

    f32x4 accq[8], accv[8];
#pragma unroll
    for (int a = 0; a < 8; ++a) {
        accq[a] = f32x4{0.f, 0.f, 0.f, 0.f};
        accv[a] = f32x4{0.f, 0.f, 0.f, 0.f};
    }

    const int gro = ((j ^ l8) << 3);

    for (int k0 = 0; k0 < 1024; k0 += 64) {
        __syncthreads();
#pragma unroll
        for (int c = 0; c < 2; ++c) {
            const int r = w * 16 + c * 8;                 // 8 waves x 16 rows
            const size_t gm = (size_t)(m0 + r + l8) * 1024 + k0 + gro;
            const size_t gn = (size_t)(n0 + r + l8) * 1024 + k0 + gro;
            glds16(xh + gm, &Ah[r * 64]);
            glds16(xl + gm, &Al[r * 64]);
            glds16(wqh + gn, &Bh[r * 64]);
            glds16(wql + gn, &Bl[r * 64]);
            glds16(wvh + gn, &Cv[r * 64]);
        }
        __syncthreads();
#pragma unroll
        for (int kc = 0; kc < 2; ++kc) {
            const int ch = (((kc * 4 + qd) ^ (i & 7)) << 3);
            const int br = (w * 16 + i) * 64 + ch;
            const short8 fbh = *(const short8*)&Bh[br];   // Wq-hi col frag
            const short8 fbl = *(const short8*)&Bl[br];   // Wq-lo col frag
            const short8 fbx = *(const short8*)&Ah[br];   // x col frag (V^T B)
#pragma unroll
            for (int mm = 0; mm < 8; ++mm) {
                const int ar = (mm * 16 + i) * 64 + ch;
                const short8 ah = *(const short8*)&Ah[ar];  // x-hi row frag
                const short8 al = *(const short8*)&Al[ar];  // x-lo row frag
                const short8 av = *(const short8*)&Cv[ar];  // Wv row frag
                accq[mm] = __builtin_amdgcn_mfma_f32_16x16x32_bf16(
                    ah, fbh, accq[mm], 0, 0, 0);
                accq[mm] = __builtin_amdgcn_mfma_f32_16x16x32_bf16(
                    al, fbh, accq[mm], 0, 0, 0);
                accq[mm] = __builtin_amdgcn_mfma_f32_16x16x32_bf16(
                    ah, fbl, accq[mm], 0, 0, 0);
                accv[mm] = __builtin_amdgcn_mfma_f32_16x16x32_bf16(
                    av, fbx, accv[mm], 0, 0, 0);
            }
        }
    }

    // Q epilogue: rows = tokens (m0 + mm*16 + qd*4 + rr), col = n0 + w*16 + i
    {
        const int col = n0 + w * 16 + i;
        const int hh = col >> 6, d = col & 63;
        const float bqc = bq[col];
#pragma unroll
        for (int mm = 0; mm < 8; ++mm)
#pragma unroll
            for (int rr = 0; rr < 4; ++rr) {
                const int row = m0 + mm * 16 + qd * 4 + rr;  // token
                const float v = accq[mm][rr] + bqc;
                const unsigned short hs = f2bf(v);
                const float lo = v - bff(hs);
                const int b = row >> 11, s = row & 2047;
                const size_t oi = ((size_t)((b << 4) + hh) * 2048 + s) * 64 + d;
                Qb[oi] = hs;
                Qlo[oi] = f2bf(lo);
            }
    }
    // V epilogue: rows = channels (n0 + mm*16 + qd*4 + rr), col token = m0+w*16+i
    {
        const int tok = m0 + w * 16 + i;
        const int b = tok >> 11, s = tok & 2047;
#pragma unroll
        for (int mm = 0; mm < 8; ++mm)
#pragma unroll
            for (int rr = 0; rr < 4; ++rr) {
                const int rch = n0 + mm * 16 + qd * 4 + rr;  // channel
                const float v = accv[mm][rr] + bv[rch];
                Vt[((size_t)(b * 1024 + rch)) * 2048 + s] = f2bf(v);
            }
    }
}

// ---------------------------------------------------------------------------
// Buckets + row norms.  q reconstructed as hi+lo from Qb/Qlo.
// ---------------------------------------------------------------------------
__global__ __launch_bounds__(256) void bucket_kernel(
    const unsigned short* __restrict__ Qb, const unsigned short* __restrict__ Qlo,
    const float* __restrict__ hp,
    int* __restrict__ buckets, float* __restrict__ rown)
{
    __shared__ float hpl[65 * 6];
    const int tid = threadIdx.x;
    if (tid < 65 * 6) hpl[tid] = hp[tid];
    __syncthreads();

    const int idx = blockIdx.x * 256 + tid;       // 65536 = 32 bh * 2048 s
    const unsigned short* qh = Qb + (size_t)idx * 64;
    const unsigned short* ql = Qlo + (size_t)idx * 64;

    float pj[6];
    float nrm = 0.f;
#pragma unroll
    for (int n = 0; n < 6; ++n) pj[n] = hpl[64 * 6 + n];
    for (int d8 = 0; d8 < 8; ++d8) {
        const short8 vh = *(const short8*)(qh + d8 * 8);
        const short8 vl = *(const short8*)(ql + d8 * 8);
#pragma unroll
        for (int e = 0; e < 8; ++e) {
            const float q = bff((unsigned short)vh[e]) + bff((unsigned short)vl[e]);
            nrm = fmaf(q, q, nrm);
#pragma unroll
            for (int n = 0; n < 6; ++n)
                pj[n] = fmaf(q, hpl[(d8 * 8 + e) * 6 + n], pj[n]);
        }
    }
    int bkt = 0;
#pragma unroll
    for (int n = 0; n < 6; ++n) bkt |= (pj[n] >= 0.f) << n;
    buckets[idx] = bkt;
    rown[idx] = nrm;
}

// ---------------------------------------------------------------------------
// Attention (EXACT verified R8 v6).  Grid (bh=32, qt=16); 4 waves; wave owns
// 32 q-rows (2 ms); K-tile 64 LDS-staged with global-side XOR swizzle.
// Fixed upper-bound softmax shift; P high-half pack.  LDS 33 KB.
// ---------------------------------------------------------------------------
__global__ __launch_bounds__(256, 2) void attn_kernel(
    const unsigned short* __restrict__ Qb, const unsigned short* __restrict__ Qlo,
    const unsigned short* __restrict__ Vt, const int* __restrict__ bks,
    const float* __restrict__ rown, float* __restrict__ out)
{
    __shared__ unsigned short Khi[64 * 64];
    __shared__ unsigned short Klo[64 * 64];
    __shared__ unsigned short Vs[64 * 64];
    __shared__ unsigned short P[4][16 * 64];
    __shared__ float smax[4];

    const int tid = threadIdx.x;
    const int w = tid >> 6, lane = tid & 63;
    const int i = lane & 15, qd = lane >> 4;
    const int l8 = lane >> 3, j = lane & 7;
    const int bh = blockIdx.x;
    const int qbase = blockIdx.y * 128 + w * 32;

    const unsigned short* Qh = Qb + (size_t)bh * 2048 * 64;
    const unsigned short* Ql = Qlo + (size_t)bh * 2048 * 64;
    const unsigned short* Vb = Vt + (size_t)bh * 64 * 2048;
    const int* bk = bks + bh * 2048;
    const float* rnh = rown + bh * 2048;
    unsigned short* Pw = &P[w][0];

    float lm = 0.f;
    for (int t = tid; t < 2048; t += 256) lm = fmaxf(lm, rnh[t]);
#pragma unroll
    for (int msk = 1; msk < 64; msk <<= 1) lm = fmaxf(lm, __shfl_xor(lm, msk));
    if (lane == 0) smax[w] = lm;
    __syncthreads();
    const float sqM = sqrtf(fmaxf(fmaxf(smax[0], smax[1]),
                                  fmaxf(smax[2], smax[3])));

    float m2row[2][4], lrun[2][4];
    int qbr[2][4];
#pragma unroll
    for (int ms = 0; ms < 2; ++ms)
#pragma unroll
        for (int r = 0; r < 4; ++r) {
            const int row = qbase + ms * 16 + qd * 4 + r;
            m2row[ms][r] = 2.84030586f * sqrtf(rnh[row]) * sqM + 0.72134754f;
            qbr[ms][r] = bk[row];
            lrun[ms][r] = 0.f;
        }

    short8 aqh0[2], aqh1[2], aql0[2], aql1[2];
#pragma unroll
    for (int ms = 0; ms < 2; ++ms) {
        const unsigned short* qp = Qh + (size_t)(qbase + ms * 16 + i) * 64 + qd * 8;
        const unsigned short* lp = Ql + (size_t)(qbase + ms * 16 + i) * 64 + qd * 8;
        aqh0[ms] = *(const short8*)qp; aqh1[ms] = *(const short8*)(qp + 32);
        aql0[ms] = *(const short8*)lp; aql1[ms] = *(const short8*)(lp + 32);
    }

    f32x4 o[2][4];
#pragma unroll
    for (int ms = 0; ms < 2; ++ms)
#pragma unroll
        for (int d = 0; d < 4; ++d) o[ms][d] = f32x4{0.f, 0.f, 0.f, 0.f};

    for (int t0 = 0; t0 < 2048; t0 += 64) {
        __syncthreads();
#pragma unroll
        for (int c2 = 0; c2 < 2; ++c2) {
            const int r = w * 16 + c2 * 8 + l8;
            const int swz = ((j ^ l8) << 3);
            glds16(Qh + (size_t)(t0 + r) * 64 + swz, &Khi[w * 1024 + c2 * 512]);
            glds16(Ql + (size_t)(t0 + r) * 64 + swz, &Klo[w * 1024 + c2 * 512]);
            glds16(Vb + (size_t)r * 2048 + t0 + swz, &Vs[w * 1024 + c2 * 512]);
        }
        __syncthreads();

        f32x4 s[2][4];
        int kb[4];
#pragma unroll
        for (int sub = 0; sub < 4; ++sub) {
            const int kr = sub * 16 + i;
            const int sw = i & 7;
            const short8 bh0 = *(const short8*)&Khi[kr * 64 + ((qd ^ sw) << 3)];
            const short8 bh1 = *(const short8*)&Khi[kr * 64 + (((qd + 4) ^ sw) << 3)];
            const short8 bl0 = *(const short8*)&Klo[kr * 64 + ((qd ^ sw) << 3)];
            const short8 bl1 = *(const short8*)&Klo[kr * 64 + (((qd + 4) ^ sw) << 3)];
            kb[sub] = bk[t0 + kr];
#pragma unroll
            for (int ms = 0; ms < 2; ++ms) {
                f32x4 t = f32x4{0.f, 0.f, 0.f, 0.f};
                t = __builtin_amdgcn_mfma_f32_16x16x32_bf16(aqh0[ms], bh0, t, 0, 0, 0);
                t = __builtin_amdgcn_mfma_f32_16x16x32_bf16(aqh1[ms], bh1, t, 0, 0, 0);
                t = __builtin_amdgcn_mfma_f32_16x16x32_bf16(aql0[ms], bh0, t, 0, 0, 0);
                t = __builtin_amdgcn_mfma_f32_16x16x32_bf16(aql1[ms], bh1, t, 0, 0, 0);
                t = __builtin_amdgcn_mfma_f32_16x16x32_bf16(aqh0[ms], bl0, t, 0, 0, 0);
                t = __builtin_amdgcn_mfma_f32_16x16x32_bf16(aqh1[ms], bl1, t, 0, 0, 0);
                s[ms][sub] = t;
            }
        }

        short8 vb0[4], vb1[4];
#pragma unroll
        for (int dsub = 0; dsub < 4; ++dsub) {
            const int dr = dsub * 16 + i;
            const int sw = i & 7;
            vb0[dsub] = *(const short8*)&Vs[dr * 64 + ((qd ^ sw) << 3)];
            vb1[dsub] = *(const short8*)&Vs[dr * 64 + (((qd + 4) ^ sw) << 3)];
        }

#pragma unroll
        for (int ms = 0; ms < 2; ++ms) {
#pragma unroll
            for (int sub = 0; sub < 4; ++sub)
#pragma unroll
                for (int r = 0; r < 4; ++r) {
                    const float c2f = (kb[sub] == qbr[ms][r]) ? 2.84030586f
                                                              : 2.79522164f;
                    const float p = exp2f(fmaf(s[ms][sub][r], c2f, -m2row[ms][r]));
                    lrun[ms][r] += p;
                    const unsigned int pu = __float_as_uint(p);
                    const int row = qd * 4 + r, col = sub * 16 + i;
                    Pw[row * 64 + (((col >> 3) ^ (row & 7)) << 3) + (col & 7)] =
                        (unsigned short)(pu >> 16);
                }
            const short8 pa0 = *(const short8*)&Pw[i * 64 + ((qd ^ (i & 7)) << 3)];
            const short8 pa1 = *(const short8*)&Pw[i * 64 + (((qd + 4) ^ (i & 7)) << 3)];
#pragma unroll
            for (int dsub = 0; dsub < 4; ++dsub) {
                o[ms][dsub] = __builtin_amdgcn_mfma_f32_16x16x32_bf16(
                    pa0, vb0[dsub], o[ms][dsub], 0, 0, 0);
                o[ms][dsub] = __builtin_amdgcn_mfma_f32_16x16x32_bf16(
                    pa1, vb1[dsub], o[ms][dsub], 0, 0, 0);
            }
        }
    }

#pragma unroll
    for (int ms = 0; ms < 2; ++ms)
#pragma unroll
        for (int r = 0; r < 4; ++r) {
#pragma unroll
            for (int msk = 1; msk < 16; msk <<= 1)
                lrun[ms][r] += __shfl_xor(lrun[ms][r], msk);
        }
    const int b = bh >> 4, h = bh & 15;
#pragma unroll
    for (int ms = 0; ms < 2; ++ms)
#pragma unroll
        for (int dsub = 0; dsub < 4; ++dsub)
#pragma unroll
            for (int r = 0; r < 4; ++r) {
                const float v = o[ms][dsub][r] / lrun[ms][r];
                const int srow = qbase + ms * 16 + qd * 4 + r;
                out[((size_t)(b * 2048 + srow)) * 1024 + h * 64 + dsub * 16 + i] = v;
            }
}

// ---------------------------------------------------------------------------
extern "C" void kernel_launch(void* const* d_in, const int* in_sizes, int n_in,
                              void* d_out, int out_size, void* d_ws, size_t ws_size,
                              hipStream_t stream)
{
    const float* x  = (const float*)d_in[0];
    const float* Wq = (const float*)d_in[1];
    const float* bq = (const float*)d_in[2];
    const float* Wv = (const float*)d_in[3];
    const float* bv = (const float*)d_in[4];
    const float* hp = (const float*)d_in[5];
    float* out = (float*)d_out;

    char* ws = (char*)d_ws;
    const size_t MB = (size_t)1 << 20;
    unsigned short* xh  = (unsigned short*)(ws);            // 8 MB
    unsigned short* xl  = (unsigned short*)(ws + 8 * MB);   // 8 MB
    unsigned short* Wqh = (unsigned short*)(ws + 16 * MB);  // 2 MB
    unsigned short* Wql = (unsigned short*)(ws + 18 * MB);  // 2 MB
    unsigned short* Wvh = (unsigned short*)(ws + 20 * MB);  // 2 MB
    unsigned short* Qb  = (unsigned short*)(ws + 22 * MB);  // 8 MB
    unsigned short* Qlo = (unsigned short*)(ws + 30 * MB);  // 8 MB
    unsigned short* Vt  = (unsigned short*)(ws + 38 * MB);  // 8 MB
    int*        buckets = (int*)(ws + 62 * MB);             // 256 KB
    float*         rown = (float*)(ws + 62 * MB + 256 * 1024);  // 256 KB

    split_all<<<dim3(6144), 256, 0, stream>>>(x, Wq, Wv, xh, xl, Wqh, Wql, Wvh);
    gemm_qv<<<dim3(256), 512, 0, stream>>>(xh, xl, Wqh, Wql, Wvh, bq, bv,
                                           Qb, Qlo, Vt);
    bucket_kernel<<<dim3(256), 256, 0, stream>>>(Qb, Qlo, hp, buckets, rown);
    attn_kernel<<<dim3(32, 16), 256, 0, stream>>>(Qb, Qlo, Vt, buckets, rown, out);
}

// Round 12
// 218.483 us; speedup vs baseline: 1.0210x; 1.0210x over previous
//
#include <hip/hip_runtime.h>

// ---------------------------------------------------------------------------
// LSH attention, MI355X.  B=2, S=2048, E=1024, H=16, Dh=64, NB=64, NH=6.
// ALL inputs/outputs are FP32.
// R12: revert to R10-best (213.2us: XCD-remapped split Q/V gemm + exact-R8
// attn) after R11's merged Q+V block regressed (+10us: merging Q and V into
// one barrier domain removed the two independently-phased blocks/CU that
// covered stage-drain stalls).  ONE change vs R10: s_setprio(1)/(0) around
// attn's MFMA clusters (T5) -- attn has 2 independent blocks/CU (the m191
// regime where setprio measured +4-7%), zero structural/traffic change,
// bit-identical outputs, bounded downside (~-1.5% worst case).
//   0) split_all: x -> xh+xl, Wq -> Wqh+Wql, Wv -> Wvh in ONE launch
//   1) gemm_qv: 512 blocks, 128x128, BK=64, bounds(256,2), XCD-remapped
//      (m-tile%8 == blk%8; Q blk i and V blk i+256 co-reside per CU)
//   2) bucket_kernel: bucket bits from hi+lo q; row |q|^2
//   3) attn_kernel: EXACT R8 structure + setprio around MFMA clusters
// ---------------------------------------------------------------------------

typedef short short8 __attribute__((ext_vector_type(8)));
typedef float f32x4 __attribute__((ext_vector_type(4)));
typedef unsigned short us4 __attribute__((ext_vector_type(4)));

__device__ __forceinline__ float bff(unsigned short h) {
    return __uint_as_float(((unsigned int)h) << 16);
}
__device__ __forceinline__ unsigned short f2bf(float f) {  // RNE, finite inputs
    unsigned int u = __float_as_uint(f);
    u += 0x7fffu + ((u >> 16) & 1u);
    return (unsigned short)(u >> 16);
}

__device__ __forceinline__ void glds16(const unsigned short* g, unsigned short* l) {
    __builtin_amdgcn_global_load_lds(
        (const __attribute__((address_space(1))) unsigned int*)g,
        (__attribute__((address_space(3))) unsigned int*)l, 16, 0, 0);
}

// ---------------------------------------------------------------------------
// Fused split: blk<4096 -> x (hi+lo); <5120 -> Wq (hi+lo); else Wv (hi).
// ---------------------------------------------------------------------------
__global__ __launch_bounds__(256) void split_all(
    const float* __restrict__ x, const float* __restrict__ Wq,
    const float* __restrict__ Wv,
    unsigned short* __restrict__ xh, unsigned short* __restrict__ xl,
    unsigned short* __restrict__ Wqh, unsigned short* __restrict__ Wql,
    unsigned short* __restrict__ Wvh)
{
    const int blk = blockIdx.x;
    const float* in;
    unsigned short *hi, *lo;
    int idx;
    if (blk < 4096) {
        idx = blk * 256 + threadIdx.x; in = x; hi = xh; lo = xl;
    } else if (blk < 5120) {
        idx = (blk - 4096) * 256 + threadIdx.x; in = Wq; hi = Wqh; lo = Wql;
    } else {
        idx = (blk - 5120) * 256 + threadIdx.x; in = Wv; hi = Wvh; lo = nullptr;
    }
    const float4 v = ((const float4*)in)[idx];
    us4 h;
    h.x = f2bf(v.x); h.y = f2bf(v.y); h.z = f2bf(v.z); h.w = f2bf(v.w);
    ((us4*)hi)[idx] = h;
    if (lo) {
        us4 l;
        l.x = f2bf(v.x - bff(h.x)); l.y = f2bf(v.y - bff(h.y));
        l.z = f2bf(v.z - bff(h.z)); l.w = f2bf(v.w - bff(h.w));
        ((us4*)lo)[idx] = l;
    }
}

// ---------------------------------------------------------------------------
// Merged projection GEMM (R10 exact).  512 blocks: b<256 Q path (3-term
// hi/lo); b>=256 V path.  128x128 tile, BK=64, LDS staged with global-side
// XOR swizzle.  Tile indices remapped so blocks sharing an x row-tile share
// an XCD (XCD = blk%8 under round-robin).  bounds(256,2) -> 2 blocks/CU.
// ---------------------------------------------------------------------------
__global__ __launch_bounds__(256, 2) void gemm_qv(
    const unsigned short* __restrict__ xh, const unsigned short* __restrict__ xl,
    const unsigned short* __restrict__ wqh, const unsigned short* __restrict__ wql,
    const unsigned short* __restrict__ wvh,
    const float* __restrict__ bq, const float* __restrict__ bv,
    unsigned short* __restrict__ Qb, unsigned short* __restrict__ Qlo,
    unsigned short* __restrict__ Vt)
{
    __shared__ unsigned short Ah[128 * 64], Al[128 * 64];
    __shared__ unsigned short Bh[128 * 64], Bl[128 * 64];

    const int tid = threadIdx.x;
    const int w = tid >> 6, lane = tid & 63;
    const int i = lane & 15, qd = lane >> 4;
    const int l8 = lane >> 3, j = lane & 7;
    const int nw = w * 32;
    const int blk = blockIdx.x;
    const bool isq = blk < 256;

    f32x4 acc[8][2];
#pragma unroll
    for (int a = 0; a < 8; ++a)
#pragma unroll
        for (int b2 = 0; b2 < 2; ++b2) acc[a][b2] = f32x4{0.f, 0.f, 0.f, 0.f};

    const int gro = ((j ^ l8) << 3);

    if (isq) {
        // XCD-locality remap: m-tile%8 == blk%8 (== XCD under round-robin)
        const int m0 = ((blk & 7) + 8 * ((blk >> 3) & 3)) * 128;  // token tile
        const int n0 = (blk >> 5) * 128;                          // channel tile
        for (int k0 = 0; k0 < 1024; k0 += 64) {
            __syncthreads();
#pragma unroll
            for (int c = 0; c < 4; ++c) {
                const int r = w * 32 + c * 8;
                const size_t gx = (size_t)(m0 + r + l8) * 1024 + k0 + gro;
                const size_t gw = (size_t)(n0 + r + l8) * 1024 + k0 + gro;
                glds16(xh + gx, &Ah[r * 64]);
                glds16(xl + gx, &Al[r * 64]);
                glds16(wqh + gw, &Bh[r * 64]);
                glds16(wql + gw, &Bl[r * 64]);
            }
            __syncthreads();
#pragma unroll
            for (int kc = 0; kc < 2; ++kc) {
                const int ch = (((kc * 4 + qd) ^ (i & 7)) << 3);
                short8 bh2[2], bl2[2];
#pragma unroll
                for (int nn = 0; nn < 2; ++nn) {
                    bh2[nn] = *(const short8*)&Bh[(nw + nn * 16 + i) * 64 + ch];
                    bl2[nn] = *(const short8*)&Bl[(nw + nn * 16 + i) * 64 + ch];
                }
#pragma unroll
                for (int mm = 0; mm < 8; ++mm) {
                    const short8 ah = *(const short8*)&Ah[(mm * 16 + i) * 64 + ch];
                    const short8 al = *(const short8*)&Al[(mm * 16 + i) * 64 + ch];
#pragma unroll
                    for (int nn = 0; nn < 2; ++nn) {
                        acc[mm][nn] = __builtin_amdgcn_mfma_f32_16x16x32_bf16(
                            ah, bh2[nn], acc[mm][nn], 0, 0, 0);
                        acc[mm][nn] = __builtin_amdgcn_mfma_f32_16x16x32_bf16(
                            al, bh2[nn], acc[mm][nn], 0, 0, 0);
                        acc[mm][nn] = __builtin_amdgcn_mfma_f32_16x16x32_bf16(
                            ah, bl2[nn], acc[mm][nn], 0, 0, 0);
                    }
                }
            }
        }
#pragma unroll
        for (int mm = 0; mm < 8; ++mm)
#pragma unroll
            for (int nn = 0; nn < 2; ++nn)
#pragma unroll
                for (int rr = 0; rr < 4; ++rr) {
                    const int row = m0 + mm * 16 + qd * 4 + rr;  // token
                    const int col = n0 + nw + nn * 16 + i;       // channel
                    const float v = acc[mm][nn][rr] + bq[col];
                    const unsigned short hs = f2bf(v);
                    const float lo = v - bff(hs);
                    const int b = row >> 11, s = row & 2047;
                    const int hh = col >> 6, d = col & 63;
                    const size_t oi = ((size_t)((b << 4) + hh) * 2048 + s) * 64 + d;
                    Qb[oi] = hs;
                    Qlo[oi] = f2bf(lo);
                }
    } else {
        const int b2 = blk - 256;
        // XCD-locality remap: token-tile%8 == b2%8 (same map as Q's x-tiles)
        const int n0 = ((b2 & 7) + 8 * ((b2 >> 3) & 3)) * 128;  // token tile
        const int m0 = (b2 >> 5) * 128;                         // channel tile
        for (int k0 = 0; k0 < 1024; k0 += 64) {
            __syncthreads();
#pragma unroll
            for (int c = 0; c < 4; ++c) {
                const int r = w * 32 + c * 8;
                glds16(wvh + (size_t)(m0 + r + l8) * 1024 + k0 + gro, &Ah[r * 64]);
                glds16(xh + (size_t)(n0 + r + l8) * 1024 + k0 + gro, &Bh[r * 64]);
            }
            __syncthreads();
#pragma unroll
            for (int kc = 0; kc < 2; ++kc) {
                const int ch = (((kc * 4 + qd) ^ (i & 7)) << 3);
                short8 bf2[2];
#pragma unroll
                for (int nn = 0; nn < 2; ++nn)
                    bf2[nn] = *(const short8*)&Bh[(nw + nn * 16 + i) * 64 + ch];
#pragma unroll
                for (int mm = 0; mm < 8; ++mm) {
                    const short8 af = *(const short8*)&Ah[(mm * 16 + i) * 64 + ch];
#pragma unroll
                    for (int nn = 0; nn < 2; ++nn)
                        acc[mm][nn] = __builtin_amdgcn_mfma_f32_16x16x32_bf16(
                            af, bf2[nn], acc[mm][nn], 0, 0, 0);
                }
            }
        }
#pragma unroll
        for (int mm = 0; mm < 8; ++mm)
#pragma unroll
            for (int nn = 0; nn < 2; ++nn)
#pragma unroll
                for (int rr = 0; rr < 4; ++rr) {
                    const int rch = m0 + mm * 16 + qd * 4 + rr;  // channel
                    const int tok = n0 + nw + nn * 16 + i;       // token
                    const float v = acc[mm][nn][rr] + bv[rch];
                    const int b = tok >> 11, s = tok & 2047;
                    Vt[((size_t)(b * 1024 + rch)) * 2048 + s] = f2bf(v);
                }
    }
}

// ---------------------------------------------------------------------------
// Buckets + row norms.  q reconstructed as hi+lo from Qb/Qlo.
// ---------------------------------------------------------------------------
__global__ __launch_bounds__(256) void bucket_kernel(
    const unsigned short* __restrict__ Qb, const unsigned short* __restrict__ Qlo,
    const float* __restrict__ hp,
    int* __restrict__ buckets, float* __restrict__ rown)
{
    __shared__ float hpl[65 * 6];
    const int tid = threadIdx.x;
    if (tid < 65 * 6) hpl[tid] = hp[tid];
    __syncthreads();

    const int idx = blockIdx.x * 256 + tid;       // 65536 = 32 bh * 2048 s
    const unsigned short* qh = Qb + (size_t)idx * 64;
    const unsigned short* ql = Qlo + (size_t)idx * 64;

    float pj[6];
    float nrm = 0.f;
#pragma unroll
    for (int n = 0; n < 6; ++n) pj[n] = hpl[64 * 6 + n];
    for (int d8 = 0; d8 < 8; ++d8) {
        const short8 vh = *(const short8*)(qh + d8 * 8);
        const short8 vl = *(const short8*)(ql + d8 * 8);
#pragma unroll
        for (int e = 0; e < 8; ++e) {
            const float q = bff((unsigned short)vh[e]) + bff((unsigned short)vl[e]);
            nrm = fmaf(q, q, nrm);
#pragma unroll
            for (int n = 0; n < 6; ++n)
                pj[n] = fmaf(q, hpl[(d8 * 8 + e) * 6 + n], pj[n]);
        }
    }
    int bkt = 0;
#pragma unroll
    for (int n = 0; n < 6; ++n) bkt |= (pj[n] >= 0.f) << n;
    buckets[idx] = bkt;
    rown[idx] = nrm;
}

// ---------------------------------------------------------------------------
// Attention (R8 structure; R12 adds setprio around MFMA clusters).  Grid
// (bh=32, qt=16); 4 waves; wave owns 32 q-rows (2 ms); K-tile 64 LDS-staged
// with global-side XOR swizzle.  Fixed upper-bound softmax shift; P
// high-half pack.  LDS 33 KB; 2 independent blocks/CU (setprio regime).
// ---------------------------------------------------------------------------
__global__ __launch_bounds__(256, 2) void attn_kernel(
    const unsigned short* __restrict__ Qb, const unsigned short* __restrict__ Qlo,
    const unsigned short* __restrict__ Vt, const int* __restrict__ bks,
    const float* __restrict__ rown, float* __restrict__ out)
{
    __shared__ unsigned short Khi[64 * 64];
    __shared__ unsigned short Klo[64 * 64];
    __shared__ unsigned short Vs[64 * 64];
    __shared__ unsigned short P[4][16 * 64];
    __shared__ float smax[4];

    const int tid = threadIdx.x;
    const int w = tid >> 6, lane = tid & 63;
    const int i = lane & 15, qd = lane >> 4;
    const int l8 = lane >> 3, j = lane & 7;
    const int bh = blockIdx.x;
    const int qbase = blockIdx.y * 128 + w * 32;

    const unsigned short* Qh = Qb + (size_t)bh * 2048 * 64;
    const unsigned short* Ql = Qlo + (size_t)bh * 2048 * 64;
    const unsigned short* Vb = Vt + (size_t)bh * 64 * 2048;
    const int* bk = bks + bh * 2048;
    const float* rnh = rown + bh * 2048;
    unsigned short* Pw = &P[w][0];

    float lm = 0.f;
    for (int t = tid; t < 2048; t += 256) lm = fmaxf(lm, rnh[t]);
#pragma unroll
    for (int msk = 1; msk < 64; msk <<= 1) lm = fmaxf(lm, __shfl_xor(lm, msk));
    if (lane == 0) smax[w] = lm;
    __syncthreads();
    const float sqM = sqrtf(fmaxf(fmaxf(smax[0], smax[1]),
                                  fmaxf(smax[2], smax[3])));

    float m2row[2][4], lrun[2][4];
    int qbr[2][4];
#pragma unroll
    for (int ms = 0; ms < 2; ++ms)
#pragma unroll
        for (int r = 0; r < 4; ++r) {
            const int row = qbase + ms * 16 + qd * 4 + r;
            m2row[ms][r] = 2.84030586f * sqrtf(rnh[row]) * sqM + 0.72134754f;
            qbr[ms][r] = bk[row];
            lrun[ms][r] = 0.f;
        }

    short8 aqh0[2], aqh1[2], aql0[2], aql1[2];
#pragma unroll
    for (int ms = 0; ms < 2; ++ms) {
        const unsigned short* qp = Qh + (size_t)(qbase + ms * 16 + i) * 64 + qd * 8;
        const unsigned short* lp = Ql + (size_t)(qbase + ms * 16 + i) * 64 + qd * 8;
        aqh0[ms] = *(const short8*)qp; aqh1[ms] = *(const short8*)(qp + 32);
        aql0[ms] = *(const short8*)lp; aql1[ms] = *(const short8*)(lp + 32);
    }

    f32x4 o[2][4];
#pragma unroll
    for (int ms = 0; ms < 2; ++ms)
#pragma unroll
        for (int d = 0; d < 4; ++d) o[ms][d] = f32x4{0.f, 0.f, 0.f, 0.f};

    for (int t0 = 0; t0 < 2048; t0 += 64) {
        __syncthreads();
#pragma unroll
        for (int c2 = 0; c2 < 2; ++c2) {
            const int r = w * 16 + c2 * 8 + l8;
            const int swz = ((j ^ l8) << 3);
            glds16(Qh + (size_t)(t0 + r) * 64 + swz, &Khi[w * 1024 + c2 * 512]);
            glds16(Ql + (size_t)(t0 + r) * 64 + swz, &Klo[w * 1024 + c2 * 512]);
            glds16(Vb + (size_t)r * 2048 + t0 + swz, &Vs[w * 1024 + c2 * 512]);
        }
        __syncthreads();

        f32x4 s[2][4];
        int kb[4];
#pragma unroll
        for (int sub = 0; sub < 4; ++sub) {
            const int kr = sub * 16 + i;
            const int sw = i & 7;
            const short8 bh0 = *(const short8*)&Khi[kr * 64 + ((qd ^ sw) << 3)];
            const short8 bh1 = *(const short8*)&Khi[kr * 64 + (((qd + 4) ^ sw) << 3)];
            const short8 bl0 = *(const short8*)&Klo[kr * 64 + ((qd ^ sw) << 3)];
            const short8 bl1 = *(const short8*)&Klo[kr * 64 + (((qd + 4) ^ sw) << 3)];
            kb[sub] = bk[t0 + kr];
            __builtin_amdgcn_s_setprio(1);          // T5: favor MFMA cluster
#pragma unroll
            for (int ms = 0; ms < 2; ++ms) {
                f32x4 t = f32x4{0.f, 0.f, 0.f, 0.f};
                t = __builtin_amdgcn_mfma_f32_16x16x32_bf16(aqh0[ms], bh0, t, 0, 0, 0);
                t = __builtin_amdgcn_mfma_f32_16x16x32_bf16(aqh1[ms], bh1, t, 0, 0, 0);
                t = __builtin_amdgcn_mfma_f32_16x16x32_bf16(aql0[ms], bh0, t, 0, 0, 0);
                t = __builtin_amdgcn_mfma_f32_16x16x32_bf16(aql1[ms], bh1, t, 0, 0, 0);
                t = __builtin_amdgcn_mfma_f32_16x16x32_bf16(aqh0[ms], bl0, t, 0, 0, 0);
                t = __builtin_amdgcn_mfma_f32_16x16x32_bf16(aqh1[ms], bl1, t, 0, 0, 0);
                s[ms][sub] = t;
            }
            __builtin_amdgcn_s_setprio(0);
        }

        short8 vb0[4], vb1[4];
#pragma unroll
        for (int dsub = 0; dsub < 4; ++dsub) {
            const int dr = dsub * 16 + i;
            const int sw = i & 7;
            vb0[dsub] = *(const short8*)&Vs[dr * 64 + ((qd ^ sw) << 3)];
            vb1[dsub] = *(const short8*)&Vs[dr * 64 + (((qd + 4) ^ sw) << 3)];
        }

#pragma unroll
        for (int ms = 0; ms < 2; ++ms) {
#pragma unroll
            for (int sub = 0; sub < 4; ++sub)
#pragma unroll
                for (int r = 0; r < 4; ++r) {
                    const float c2f = (kb[sub] == qbr[ms][r]) ? 2.84030586f
                                                              : 2.79522164f;
                    const float p = exp2f(fmaf(s[ms][sub][r], c2f, -m2row[ms][r]));
                    lrun[ms][r] += p;
                    const unsigned int pu = __float_as_uint(p);
                    const int row = qd * 4 + r, col = sub * 16 + i;
                    Pw[row * 64 + (((col >> 3) ^ (row & 7)) << 3) + (col & 7)] =
                        (unsigned short)(pu >> 16);
                }
            const short8 pa0 = *(const short8*)&Pw[i * 64 + ((qd ^ (i & 7)) << 3)];
            const short8 pa1 = *(const short8*)&Pw[i * 64 + (((qd + 4) ^ (i & 7)) << 3)];
            __builtin_amdgcn_s_setprio(1);          // T5: favor PV MFMA cluster
#pragma unroll
            for (int dsub = 0; dsub < 4; ++dsub) {
                o[ms][dsub] = __builtin_amdgcn_mfma_f32_16x16x32_bf16(
                    pa0, vb0[dsub], o[ms][dsub], 0, 0, 0);
                o[ms][dsub] = __builtin_amdgcn_mfma_f32_16x16x32_bf16(
                    pa1, vb1[dsub], o[ms][dsub], 0, 0, 0);
            }
            __builtin_amdgcn_s_setprio(0);
        }
    }

#pragma unroll
    for (int ms = 0; ms < 2; ++ms)
#pragma unroll
        for (int r = 0; r < 4; ++r) {
#pragma unroll
            for (int msk = 1; msk < 16; msk <<= 1)
                lrun[ms][r] += __shfl_xor(lrun[ms][r], msk);
        }
    const int b = bh >> 4, h = bh & 15;
#pragma unroll
    for (int ms = 0; ms < 2; ++ms)
#pragma unroll
        for (int dsub = 0; dsub < 4; ++dsub)
#pragma unroll
            for (int r = 0; r < 4; ++r) {
                const float v = o[ms][dsub][r] / lrun[ms][r];
                const int srow = qbase + ms * 16 + qd * 4 + r;
                out[((size_t)(b * 2048 + srow)) * 1024 + h * 64 + dsub * 16 + i] = v;
            }
}

// ---------------------------------------------------------------------------
extern "C" void kernel_launch(void* const* d_in, const int* in_sizes, int n_in,
                              void* d_out, int out_size, void* d_ws, size_t ws_size,
                              hipStream_t stream)
{
    const float* x  = (const float*)d_in[0];
    const float* Wq = (const float*)d_in[1];
    const float* bq = (const float*)d_in[2];
    const float* Wv = (const float*)d_in[3];
    const float* bv = (const float*)d_in[4];
    const float* hp = (const float*)d_in[5];
    float* out = (float*)d_out;

    char* ws = (char*)d_ws;
    const size_t MB = (size_t)1 << 20;
    unsigned short* xh  = (unsigned short*)(ws);            // 8 MB
    unsigned short* xl  = (unsigned short*)(ws + 8 * MB);   // 8 MB
    unsigned short* Wqh = (unsigned short*)(ws + 16 * MB);  // 2 MB
    unsigned short* Wql = (unsigned short*)(ws + 18 * MB);  // 2 MB
    unsigned short* Wvh = (unsigned short*)(ws + 20 * MB);  // 2 MB
    unsigned short* Qb  = (unsigned short*)(ws + 22 * MB);  // 8 MB
    unsigned short* Qlo = (unsigned short*)(ws + 30 * MB);  // 8 MB
    unsigned short* Vt  = (unsigned short*)(ws + 38 * MB);  // 8 MB
    int*        buckets = (int*)(ws + 62 * MB);             // 256 KB
    float*         rown = (float*)(ws + 62 * MB + 256 * 1024);  // 256 KB

    split_all<<<dim3(6144), 256, 0, stream>>>(x, Wq, Wv, xh, xl, Wqh, Wql, Wvh);
    gemm_qv<<<dim3(512), 256, 0, stream>>>(xh, xl, Wqh, Wql, Wvh, bq, bv,
                                           Qb, Qlo, Vt);
    bucket_kernel<<<dim3(256), 256, 0, stream>>>(Qb, Qlo, hp, buckets, rown);
    attn_kernel<<<dim3(32, 16), 256, 0, stream>>>(Qb, Qlo, Vt, buckets, rown, out);
}

// Round 13
// 212.346 us; speedup vs baseline: 1.0505x; 1.0289x over previous
//
#include <hip/hip_runtime.h>

// ---------------------------------------------------------------------------
// LSH attention, MI355X.  B=2, S=2048, E=1024, H=16, Dh=64, NB=64, NH=6.
// ALL inputs/outputs are FP32.
// R13: EXACT revert to R10-best (213.2us measured).  R12's setprio regressed
// attn 101.5->115.0 (VGPR 128->124: the intrinsic perturbed codegen, and in
// a barrier-synced 4-wave block priority toggling penalizes the co-resident
// block -- m190 GEMM-null regime dominates).  Session ledger: XCD-locality
// remap is the only measured win (+3.6us); occupancy (R2/R4/R9), barrier
// restructure (R1/R3/R7/R11), and scheduler hints (R12) all regressed.
//   0) split_all: x -> xh+xl, Wq -> Wqh+Wql, Wv -> Wvh in ONE launch
//   1) gemm_qv: 512 blocks, 128x128, BK=64, bounds(256,2), XCD-remapped
//      (m-tile%8 == blk%8; Q blk i and V blk i+256 co-reside per CU)
//   2) bucket_kernel: bucket bits from hi+lo q; row |q|^2
//   3) attn_kernel: EXACT verified R8 (grid (32,16), 4 waves x 32 q-rows)
// ---------------------------------------------------------------------------

typedef short short8 __attribute__((ext_vector_type(8)));
typedef float f32x4 __attribute__((ext_vector_type(4)));
typedef unsigned short us4 __attribute__((ext_vector_type(4)));

__device__ __forceinline__ float bff(unsigned short h) {
    return __uint_as_float(((unsigned int)h) << 16);
}
__device__ __forceinline__ unsigned short f2bf(float f) {  // RNE, finite inputs
    unsigned int u = __float_as_uint(f);
    u += 0x7fffu + ((u >> 16) & 1u);
    return (unsigned short)(u >> 16);
}

__device__ __forceinline__ void glds16(const unsigned short* g, unsigned short* l) {
    __builtin_amdgcn_global_load_lds(
        (const __attribute__((address_space(1))) unsigned int*)g,
        (__attribute__((address_space(3))) unsigned int*)l, 16, 0, 0);
}

// ---------------------------------------------------------------------------
// Fused split: blk<4096 -> x (hi+lo); <5120 -> Wq (hi+lo); else Wv (hi).
// ---------------------------------------------------------------------------
__global__ __launch_bounds__(256) void split_all(
    const float* __restrict__ x, const float* __restrict__ Wq,
    const float* __restrict__ Wv,
    unsigned short* __restrict__ xh, unsigned short* __restrict__ xl,
    unsigned short* __restrict__ Wqh, unsigned short* __restrict__ Wql,
    unsigned short* __restrict__ Wvh)
{
    const int blk = blockIdx.x;
    const float* in;
    unsigned short *hi, *lo;
    int idx;
    if (blk < 4096) {
        idx = blk * 256 + threadIdx.x; in = x; hi = xh; lo = xl;
    } else if (blk < 5120) {
        idx = (blk - 4096) * 256 + threadIdx.x; in = Wq; hi = Wqh; lo = Wql;
    } else {
        idx = (blk - 5120) * 256 + threadIdx.x; in = Wv; hi = Wvh; lo = nullptr;
    }
    const float4 v = ((const float4*)in)[idx];
    us4 h;
    h.x = f2bf(v.x); h.y = f2bf(v.y); h.z = f2bf(v.z); h.w = f2bf(v.w);
    ((us4*)hi)[idx] = h;
    if (lo) {
        us4 l;
        l.x = f2bf(v.x - bff(h.x)); l.y = f2bf(v.y - bff(h.y));
        l.z = f2bf(v.z - bff(h.z)); l.w = f2bf(v.w - bff(h.w));
        ((us4*)lo)[idx] = l;
    }
}

// ---------------------------------------------------------------------------
// Merged projection GEMM (R10 exact).  512 blocks: b<256 Q path (3-term
// hi/lo); b>=256 V path.  128x128 tile, BK=64, LDS staged with global-side
// XOR swizzle.  Tile indices remapped so blocks sharing an x row-tile share
// an XCD (XCD = blk%8 under round-robin).  bounds(256,2) -> 2 blocks/CU.
// ---------------------------------------------------------------------------
__global__ __launch_bounds__(256, 2) void gemm_qv(
    const unsigned short* __restrict__ xh, const unsigned short* __restrict__ xl,
    const unsigned short* __restrict__ wqh, const unsigned short* __restrict__ wql,
    const unsigned short* __restrict__ wvh,
    const float* __restrict__ bq, const float* __restrict__ bv,
    unsigned short* __restrict__ Qb, unsigned short* __restrict__ Qlo,
    unsigned short* __restrict__ Vt)
{
    __shared__ unsigned short Ah[128 * 64], Al[128 * 64];
    __shared__ unsigned short Bh[128 * 64], Bl[128 * 64];

    const int tid = threadIdx.x;
    const int w = tid >> 6, lane = tid & 63;
    const int i = lane & 15, qd = lane >> 4;
    const int l8 = lane >> 3, j = lane & 7;
    const int nw = w * 32;
    const int blk = blockIdx.x;
    const bool isq = blk < 256;

    f32x4 acc[8][2];
#pragma unroll
    for (int a = 0; a < 8; ++a)
#pragma unroll
        for (int b2 = 0; b2 < 2; ++b2) acc[a][b2] = f32x4{0.f, 0.f, 0.f, 0.f};

    const int gro = ((j ^ l8) << 3);

    if (isq) {
        // XCD-locality remap: m-tile%8 == blk%8 (== XCD under round-robin)
        const int m0 = ((blk & 7) + 8 * ((blk >> 3) & 3)) * 128;  // token tile
        const int n0 = (blk >> 5) * 128;                          // channel tile
        for (int k0 = 0; k0 < 1024; k0 += 64) {
            __syncthreads();
#pragma unroll
            for (int c = 0; c < 4; ++c) {
                const int r = w * 32 + c * 8;
                const size_t gx = (size_t)(m0 + r + l8) * 1024 + k0 + gro;
                const size_t gw = (size_t)(n0 + r + l8) * 1024 + k0 + gro;
                glds16(xh + gx, &Ah[r * 64]);
                glds16(xl + gx, &Al[r * 64]);
                glds16(wqh + gw, &Bh[r * 64]);
                glds16(wql + gw, &Bl[r * 64]);
            }
            __syncthreads();
#pragma unroll
            for (int kc = 0; kc < 2; ++kc) {
                const int ch = (((kc * 4 + qd) ^ (i & 7)) << 3);
                short8 bh2[2], bl2[2];
#pragma unroll
                for (int nn = 0; nn < 2; ++nn) {
                    bh2[nn] = *(const short8*)&Bh[(nw + nn * 16 + i) * 64 + ch];
                    bl2[nn] = *(const short8*)&Bl[(nw + nn * 16 + i) * 64 + ch];
                }
#pragma unroll
                for (int mm = 0; mm < 8; ++mm) {
                    const short8 ah = *(const short8*)&Ah[(mm * 16 + i) * 64 + ch];
                    const short8 al = *(const short8*)&Al[(mm * 16 + i) * 64 + ch];
#pragma unroll
                    for (int nn = 0; nn < 2; ++nn) {
                        acc[mm][nn] = __builtin_amdgcn_mfma_f32_16x16x32_bf16(
                            ah, bh2[nn], acc[mm][nn], 0, 0, 0);
                        acc[mm][nn] = __builtin_amdgcn_mfma_f32_16x16x32_bf16(
                            al, bh2[nn], acc[mm][nn], 0, 0, 0);
                        acc[mm][nn] = __builtin_amdgcn_mfma_f32_16x16x32_bf16(
                            ah, bl2[nn], acc[mm][nn], 0, 0, 0);
                    }
                }
            }
        }
#pragma unroll
        for (int mm = 0; mm < 8; ++mm)
#pragma unroll
            for (int nn = 0; nn < 2; ++nn)
#pragma unroll
                for (int rr = 0; rr < 4; ++rr) {
                    const int row = m0 + mm * 16 + qd * 4 + rr;  // token
                    const int col = n0 + nw + nn * 16 + i;       // channel
                    const float v = acc[mm][nn][rr] + bq[col];
                    const unsigned short hs = f2bf(v);
                    const float lo = v - bff(hs);
                    const int b = row >> 11, s = row & 2047;
                    const int hh = col >> 6, d = col & 63;
                    const size_t oi = ((size_t)((b << 4) + hh) * 2048 + s) * 64 + d;
                    Qb[oi] = hs;
                    Qlo[oi] = f2bf(lo);
                }
    } else {
        const int b2 = blk - 256;
        // XCD-locality remap: token-tile%8 == b2%8 (same map as Q's x-tiles)
        const int n0 = ((b2 & 7) + 8 * ((b2 >> 3) & 3)) * 128;  // token tile
        const int m0 = (b2 >> 5) * 128;                         // channel tile
        for (int k0 = 0; k0 < 1024; k0 += 64) {
            __syncthreads();
#pragma unroll
            for (int c = 0; c < 4; ++c) {
                const int r = w * 32 + c * 8;
                glds16(wvh + (size_t)(m0 + r + l8) * 1024 + k0 + gro, &Ah[r * 64]);
                glds16(xh + (size_t)(n0 + r + l8) * 1024 + k0 + gro, &Bh[r * 64]);
            }
            __syncthreads();
#pragma unroll
            for (int kc = 0; kc < 2; ++kc) {
                const int ch = (((kc * 4 + qd) ^ (i & 7)) << 3);
                short8 bf2[2];
#pragma unroll
                for (int nn = 0; nn < 2; ++nn)
                    bf2[nn] = *(const short8*)&Bh[(nw + nn * 16 + i) * 64 + ch];
#pragma unroll
                for (int mm = 0; mm < 8; ++mm) {
                    const short8 af = *(const short8*)&Ah[(mm * 16 + i) * 64 + ch];
#pragma unroll
                    for (int nn = 0; nn < 2; ++nn)
                        acc[mm][nn] = __builtin_amdgcn_mfma_f32_16x16x32_bf16(
                            af, bf2[nn], acc[mm][nn], 0, 0, 0);
                }
            }
        }
#pragma unroll
        for (int mm = 0; mm < 8; ++mm)
#pragma unroll
            for (int nn = 0; nn < 2; ++nn)
#pragma unroll
                for (int rr = 0; rr < 4; ++rr) {
                    const int rch = m0 + mm * 16 + qd * 4 + rr;  // channel
                    const int tok = n0 + nw + nn * 16 + i;       // token
                    const float v = acc[mm][nn][rr] + bv[rch];
                    const int b = tok >> 11, s = tok & 2047;
                    Vt[((size_t)(b * 1024 + rch)) * 2048 + s] = f2bf(v);
                }
    }
}

// ---------------------------------------------------------------------------
// Buckets + row norms.  q reconstructed as hi+lo from Qb/Qlo.
// ---------------------------------------------------------------------------
__global__ __launch_bounds__(256) void bucket_kernel(
    const unsigned short* __restrict__ Qb, const unsigned short* __restrict__ Qlo,
    const float* __restrict__ hp,
    int* __restrict__ buckets, float* __restrict__ rown)
{
    __shared__ float hpl[65 * 6];
    const int tid = threadIdx.x;
    if (tid < 65 * 6) hpl[tid] = hp[tid];
    __syncthreads();

    const int idx = blockIdx.x * 256 + tid;       // 65536 = 32 bh * 2048 s
    const unsigned short* qh = Qb + (size_t)idx * 64;
    const unsigned short* ql = Qlo + (size_t)idx * 64;

    float pj[6];
    float nrm = 0.f;
#pragma unroll
    for (int n = 0; n < 6; ++n) pj[n] = hpl[64 * 6 + n];
    for (int d8 = 0; d8 < 8; ++d8) {
        const short8 vh = *(const short8*)(qh + d8 * 8);
        const short8 vl = *(const short8*)(ql + d8 * 8);
#pragma unroll
        for (int e = 0; e < 8; ++e) {
            const float q = bff((unsigned short)vh[e]) + bff((unsigned short)vl[e]);
            nrm = fmaf(q, q, nrm);
#pragma unroll
            for (int n = 0; n < 6; ++n)
                pj[n] = fmaf(q, hpl[(d8 * 8 + e) * 6 + n], pj[n]);
        }
    }
    int bkt = 0;
#pragma unroll
    for (int n = 0; n < 6; ++n) bkt |= (pj[n] >= 0.f) << n;
    buckets[idx] = bkt;
    rown[idx] = nrm;
}

// ---------------------------------------------------------------------------
// Attention (EXACT verified R8 v6).  Grid (bh=32, qt=16); 4 waves; wave owns
// 32 q-rows (2 ms); K-tile 64 LDS-staged with global-side XOR swizzle.
// Fixed upper-bound softmax shift; P high-half pack.  LDS 33 KB.
// ---------------------------------------------------------------------------
__global__ __launch_bounds__(256, 2) void attn_kernel(
    const unsigned short* __restrict__ Qb, const unsigned short* __restrict__ Qlo,
    const unsigned short* __restrict__ Vt, const int* __restrict__ bks,
    const float* __restrict__ rown, float* __restrict__ out)
{
    __shared__ unsigned short Khi[64 * 64];
    __shared__ unsigned short Klo[64 * 64];
    __shared__ unsigned short Vs[64 * 64];
    __shared__ unsigned short P[4][16 * 64];
    __shared__ float smax[4];

    const int tid = threadIdx.x;
    const int w = tid >> 6, lane = tid & 63;
    const int i = lane & 15, qd = lane >> 4;
    const int l8 = lane >> 3, j = lane & 7;
    const int bh = blockIdx.x;
    const int qbase = blockIdx.y * 128 + w * 32;

    const unsigned short* Qh = Qb + (size_t)bh * 2048 * 64;
    const unsigned short* Ql = Qlo + (size_t)bh * 2048 * 64;
    const unsigned short* Vb = Vt + (size_t)bh * 64 * 2048;
    const int* bk = bks + bh * 2048;
    const float* rnh = rown + bh * 2048;
    unsigned short* Pw = &P[w][0];

    float lm = 0.f;
    for (int t = tid; t < 2048; t += 256) lm = fmaxf(lm, rnh[t]);
#pragma unroll
    for (int msk = 1; msk < 64; msk <<= 1) lm = fmaxf(lm, __shfl_xor(lm, msk));
    if (lane == 0) smax[w] = lm;
    __syncthreads();
    const float sqM = sqrtf(fmaxf(fmaxf(smax[0], smax[1]),
                                  fmaxf(smax[2], smax[3])));

    float m2row[2][4], lrun[2][4];
    int qbr[2][4];
#pragma unroll
    for (int ms = 0; ms < 2; ++ms)
#pragma unroll
        for (int r = 0; r < 4; ++r) {
            const int row = qbase + ms * 16 + qd * 4 + r;
            m2row[ms][r] = 2.84030586f * sqrtf(rnh[row]) * sqM + 0.72134754f;
            qbr[ms][r] = bk[row];
            lrun[ms][r] = 0.f;
        }

    short8 aqh0[2], aqh1[2], aql0[2], aql1[2];
#pragma unroll
    for (int ms = 0; ms < 2; ++ms) {
        const unsigned short* qp = Qh + (size_t)(qbase + ms * 16 + i) * 64 + qd * 8;
        const unsigned short* lp = Ql + (size_t)(qbase + ms * 16 + i) * 64 + qd * 8;
        aqh0[ms] = *(const short8*)qp; aqh1[ms] = *(const short8*)(qp + 32);
        aql0[ms] = *(const short8*)lp; aql1[ms] = *(const short8*)(lp + 32);
    }

    f32x4 o[2][4];
#pragma unroll
    for (int ms = 0; ms < 2; ++ms)
#pragma unroll
        for (int d = 0; d < 4; ++d) o[ms][d] = f32x4{0.f, 0.f, 0.f, 0.f};

    for (int t0 = 0; t0 < 2048; t0 += 64) {
        __syncthreads();
#pragma unroll
        for (int c2 = 0; c2 < 2; ++c2) {
            const int r = w * 16 + c2 * 8 + l8;
            const int swz = ((j ^ l8) << 3);
            glds16(Qh + (size_t)(t0 + r) * 64 + swz, &Khi[w * 1024 + c2 * 512]);
            glds16(Ql + (size_t)(t0 + r) * 64 + swz, &Klo[w * 1024 + c2 * 512]);
            glds16(Vb + (size_t)r * 2048 + t0 + swz, &Vs[w * 1024 + c2 * 512]);
        }
        __syncthreads();

        f32x4 s[2][4];
        int kb[4];
#pragma unroll
        for (int sub = 0; sub < 4; ++sub) {
            const int kr = sub * 16 + i;
            const int sw = i & 7;
            const short8 bh0 = *(const short8*)&Khi[kr * 64 + ((qd ^ sw) << 3)];
            const short8 bh1 = *(const short8*)&Khi[kr * 64 + (((qd + 4) ^ sw) << 3)];
            const short8 bl0 = *(const short8*)&Klo[kr * 64 + ((qd ^ sw) << 3)];
            const short8 bl1 = *(const short8*)&Klo[kr * 64 + (((qd + 4) ^ sw) << 3)];
            kb[sub] = bk[t0 + kr];
#pragma unroll
            for (int ms = 0; ms < 2; ++ms) {
                f32x4 t = f32x4{0.f, 0.f, 0.f, 0.f};
                t = __builtin_amdgcn_mfma_f32_16x16x32_bf16(aqh0[ms], bh0, t, 0, 0, 0);
                t = __builtin_amdgcn_mfma_f32_16x16x32_bf16(aqh1[ms], bh1, t, 0, 0, 0);
                t = __builtin_amdgcn_mfma_f32_16x16x32_bf16(aql0[ms], bh0, t, 0, 0, 0);
                t = __builtin_amdgcn_mfma_f32_16x16x32_bf16(aql1[ms], bh1, t, 0, 0, 0);
                t = __builtin_amdgcn_mfma_f32_16x16x32_bf16(aqh0[ms], bl0, t, 0, 0, 0);
                t = __builtin_amdgcn_mfma_f32_16x16x32_bf16(aqh1[ms], bl1, t, 0, 0, 0);
                s[ms][sub] = t;
            }
        }

        short8 vb0[4], vb1[4];
#pragma unroll
        for (int dsub = 0; dsub < 4; ++dsub) {
            const int dr = dsub * 16 + i;
            const int sw = i & 7;
            vb0[dsub] = *(const short8*)&Vs[dr * 64 + ((qd ^ sw) << 3)];
            vb1[dsub] = *(const short8*)&Vs[dr * 64 + (((qd + 4) ^ sw) << 3)];
        }

#pragma unroll
        for (int ms = 0; ms < 2; ++ms) {
#pragma unroll
            for (int sub = 0; sub < 4; ++sub)
#pragma unroll
                for (int r = 0; r < 4; ++r) {
                    const float c2f = (kb[sub] == qbr[ms][r]) ? 2.84030586f
                                                              : 2.79522164f;
                    const float p = exp2f(fmaf(s[ms][sub][r], c2f, -m2row[ms][r]));
                    lrun[ms][r] += p;
                    const unsigned int pu = __float_as_uint(p);
                    const int row = qd * 4 + r, col = sub * 16 + i;
                    Pw[row * 64 + (((col >> 3) ^ (row & 7)) << 3) + (col & 7)] =
                        (unsigned short)(pu >> 16);
                }
            const short8 pa0 = *(const short8*)&Pw[i * 64 + ((qd ^ (i & 7)) << 3)];
            const short8 pa1 = *(const short8*)&Pw[i * 64 + (((qd + 4) ^ (i & 7)) << 3)];
#pragma unroll
            for (int dsub = 0; dsub < 4; ++dsub) {
                o[ms][dsub] = __builtin_amdgcn_mfma_f32_16x16x32_bf16(
                    pa0, vb0[dsub], o[ms][dsub], 0, 0, 0);
                o[ms][dsub] = __builtin_amdgcn_mfma_f32_16x16x32_bf16(
                    pa1, vb1[dsub], o[ms][dsub], 0, 0, 0);
            }
        }
    }

#pragma unroll
    for (int ms = 0; ms < 2; ++ms)
#pragma unroll
        for (int r = 0; r < 4; ++r) {
#pragma unroll
            for (int msk = 1; msk < 16; msk <<= 1)
                lrun[ms][r] += __shfl_xor(lrun[ms][r], msk);
        }
    const int b = bh >> 4, h = bh & 15;
#pragma unroll
    for (int ms = 0; ms < 2; ++ms)
#pragma unroll
        for (int dsub = 0; dsub < 4; ++dsub)
#pragma unroll
            for (int r = 0; r < 4; ++r) {
                const float v = o[ms][dsub][r] / lrun[ms][r];
                const int srow = qbase + ms * 16 + qd * 4 + r;
                out[((size_t)(b * 2048 + srow)) * 1024 + h * 64 + dsub * 16 + i] = v;
            }
}

// ---------------------------------------------------------------------------
extern "C" void kernel_launch(void* const* d_in, const int* in_sizes, int n_in,
                              void* d_out, int out_size, void* d_ws, size_t ws_size,
                              hipStream_t stream)
{
    const float* x  = (const float*)d_in[0];
    const float* Wq = (const float*)d_in[1];
    const float* bq = (const float*)d_in[2];
    const float* Wv = (const float*)d_in[3];
    const float* bv = (const float*)d_in[4];
    const float* hp = (const float*)d_in[5];
    float* out = (float*)d_out;

    char* ws = (char*)d_ws;
    const size_t MB = (size_t)1 << 20;
    unsigned short* xh  = (unsigned short*)(ws);            // 8 MB
    unsigned short* xl  = (unsigned short*)(ws + 8 * MB);   // 8 MB
    unsigned short* Wqh = (unsigned short*)(ws + 16 * MB);  // 2 MB
    unsigned short* Wql = (unsigned short*)(ws + 18 * MB);  // 2 MB
    unsigned short* Wvh = (unsigned short*)(ws + 20 * MB);  // 2 MB
    unsigned short* Qb  = (unsigned short*)(ws + 22 * MB);  // 8 MB
    unsigned short* Qlo = (unsigned short*)(ws + 30 * MB);  // 8 MB
    unsigned short* Vt  = (unsigned short*)(ws + 38 * MB);  // 8 MB
    int*        buckets = (int*)(ws + 62 * MB);             // 256 KB
    float*         rown = (float*)(ws + 62 * MB + 256 * 1024);  // 256 KB

    split_all<<<dim3(6144), 256, 0, stream>>>(x, Wq, Wv, xh, xl, Wqh, Wql, Wvh);
    gemm_qv<<<dim3(512), 256, 0, stream>>>(xh, xl, Wqh, Wql, Wvh, bq, bv,
                                           Qb, Qlo, Vt);
    bucket_kernel<<<dim3(256), 256, 0, stream>>>(Qb, Qlo, hp, buckets, rown);
    attn_kernel<<<dim3(32, 16), 256, 0, stream>>>(Qb, Qlo, Vt, buckets, rown, out);
}

// Round 14
// 212.224 us; speedup vs baseline: 1.0511x; 1.0006x over previous
//
#include <hip/hip_runtime.h>

// ---------------------------------------------------------------------------
// LSH attention, MI355X.  B=2, S=2048, E=1024, H=16, Dh=64, NB=64, NH=6.
// ALL inputs/outputs are FP32.
// R14 (TERMINAL): exact R10/R13 configuration, twice-verified at 213.2 /
// 212.3 us.  Session converged: XCD-locality remap was the only measured
// win (+3.6us); occupancy (R2/R4/R9), barrier restructure (R1/R3/R7/R11),
// and scheduler hints (R12) all regressed.  attn is latency-bound (MfmaUtil
// 27%, HBM 3.7%) in a 2-barrier loop at 2 blocks/CU; the remaining paths
// (in-register softmax via swapped QK^T, 8-phase counted-vmcnt pipeline)
// are co-designed rewrites that cannot be de-risked one-shot-per-round.
//   0) split_all: x -> xh+xl, Wq -> Wqh+Wql, Wv -> Wvh in ONE launch
//   1) gemm_qv: 512 blocks, 128x128, BK=64, bounds(256,2), XCD-remapped
//      (m-tile%8 == blk%8; Q blk i and V blk i+256 co-reside per CU and
//      read the SAME x-tile -> L1/L2 reuse)
//   2) bucket_kernel: bucket bits from hi+lo q; row |q|^2
//   3) attn_kernel: EXACT verified R8 (grid (32,16), 4 waves x 32 q-rows)
// ---------------------------------------------------------------------------

typedef short short8 __attribute__((ext_vector_type(8)));
typedef float f32x4 __attribute__((ext_vector_type(4)));
typedef unsigned short us4 __attribute__((ext_vector_type(4)));

__device__ __forceinline__ float bff(unsigned short h) {
    return __uint_as_float(((unsigned int)h) << 16);
}
__device__ __forceinline__ unsigned short f2bf(float f) {  // RNE, finite inputs
    unsigned int u = __float_as_uint(f);
    u += 0x7fffu + ((u >> 16) & 1u);
    return (unsigned short)(u >> 16);
}

__device__ __forceinline__ void glds16(const unsigned short* g, unsigned short* l) {
    __builtin_amdgcn_global_load_lds(
        (const __attribute__((address_space(1))) unsigned int*)g,
        (__attribute__((address_space(3))) unsigned int*)l, 16, 0, 0);
}

// ---------------------------------------------------------------------------
// Fused split: blk<4096 -> x (hi+lo); <5120 -> Wq (hi+lo); else Wv (hi).
// ---------------------------------------------------------------------------
__global__ __launch_bounds__(256) void split_all(
    const float* __restrict__ x, const float* __restrict__ Wq,
    const float* __restrict__ Wv,
    unsigned short* __restrict__ xh, unsigned short* __restrict__ xl,
    unsigned short* __restrict__ Wqh, unsigned short* __restrict__ Wql,
    unsigned short* __restrict__ Wvh)
{
    const int blk = blockIdx.x;
    const float* in;
    unsigned short *hi, *lo;
    int idx;
    if (blk < 4096) {
        idx = blk * 256 + threadIdx.x; in = x; hi = xh; lo = xl;
    } else if (blk < 5120) {
        idx = (blk - 4096) * 256 + threadIdx.x; in = Wq; hi = Wqh; lo = Wql;
    } else {
        idx = (blk - 5120) * 256 + threadIdx.x; in = Wv; hi = Wvh; lo = nullptr;
    }
    const float4 v = ((const float4*)in)[idx];
    us4 h;
    h.x = f2bf(v.x); h.y = f2bf(v.y); h.z = f2bf(v.z); h.w = f2bf(v.w);
    ((us4*)hi)[idx] = h;
    if (lo) {
        us4 l;
        l.x = f2bf(v.x - bff(h.x)); l.y = f2bf(v.y - bff(h.y));
        l.z = f2bf(v.z - bff(h.z)); l.w = f2bf(v.w - bff(h.w));
        ((us4*)lo)[idx] = l;
    }
}

// ---------------------------------------------------------------------------
// Merged projection GEMM (R10 exact).  512 blocks: b<256 Q path (3-term
// hi/lo); b>=256 V path.  128x128 tile, BK=64, LDS staged with global-side
// XOR swizzle.  Tile indices remapped so blocks sharing an x row-tile share
// an XCD (XCD = blk%8 under round-robin).  bounds(256,2) -> 2 blocks/CU.
// ---------------------------------------------------------------------------
__global__ __launch_bounds__(256, 2) void gemm_qv(
    const unsigned short* __restrict__ xh, const unsigned short* __restrict__ xl,
    const unsigned short* __restrict__ wqh, const unsigned short* __restrict__ wql,
    const unsigned short* __restrict__ wvh,
    const float* __restrict__ bq, const float* __restrict__ bv,
    unsigned short* __restrict__ Qb, unsigned short* __restrict__ Qlo,
    unsigned short* __restrict__ Vt)
{
    __shared__ unsigned short Ah[128 * 64], Al[128 * 64];
    __shared__ unsigned short Bh[128 * 64], Bl[128 * 64];

    const int tid = threadIdx.x;
    const int w = tid >> 6, lane = tid & 63;
    const int i = lane & 15, qd = lane >> 4;
    const int l8 = lane >> 3, j = lane & 7;
    const int nw = w * 32;
    const int blk = blockIdx.x;
    const bool isq = blk < 256;

    f32x4 acc[8][2];
#pragma unroll
    for (int a = 0; a < 8; ++a)
#pragma unroll
        for (int b2 = 0; b2 < 2; ++b2) acc[a][b2] = f32x4{0.f, 0.f, 0.f, 0.f};

    const int gro = ((j ^ l8) << 3);

    if (isq) {
        // XCD-locality remap: m-tile%8 == blk%8 (== XCD under round-robin)
        const int m0 = ((blk & 7) + 8 * ((blk >> 3) & 3)) * 128;  // token tile
        const int n0 = (blk >> 5) * 128;                          // channel tile
        for (int k0 = 0; k0 < 1024; k0 += 64) {
            __syncthreads();
#pragma unroll
            for (int c = 0; c < 4; ++c) {
                const int r = w * 32 + c * 8;
                const size_t gx = (size_t)(m0 + r + l8) * 1024 + k0 + gro;
                const size_t gw = (size_t)(n0 + r + l8) * 1024 + k0 + gro;
                glds16(xh + gx, &Ah[r * 64]);
                glds16(xl + gx, &Al[r * 64]);
                glds16(wqh + gw, &Bh[r * 64]);
                glds16(wql + gw, &Bl[r * 64]);
            }
            __syncthreads();
#pragma unroll
            for (int kc = 0; kc < 2; ++kc) {
                const int ch = (((kc * 4 + qd) ^ (i & 7)) << 3);
                short8 bh2[2], bl2[2];
#pragma unroll
                for (int nn = 0; nn < 2; ++nn) {
                    bh2[nn] = *(const short8*)&Bh[(nw + nn * 16 + i) * 64 + ch];
                    bl2[nn] = *(const short8*)&Bl[(nw + nn * 16 + i) * 64 + ch];
                }
#pragma unroll
                for (int mm = 0; mm < 8; ++mm) {
                    const short8 ah = *(const short8*)&Ah[(mm * 16 + i) * 64 + ch];
                    const short8 al = *(const short8*)&Al[(mm * 16 + i) * 64 + ch];
#pragma unroll
                    for (int nn = 0; nn < 2; ++nn) {
                        acc[mm][nn] = __builtin_amdgcn_mfma_f32_16x16x32_bf16(
                            ah, bh2[nn], acc[mm][nn], 0, 0, 0);
                        acc[mm][nn] = __builtin_amdgcn_mfma_f32_16x16x32_bf16(
                            al, bh2[nn], acc[mm][nn], 0, 0, 0);
                        acc[mm][nn] = __builtin_amdgcn_mfma_f32_16x16x32_bf16(
                            ah, bl2[nn], acc[mm][nn], 0, 0, 0);
                    }
                }
            }
        }
#pragma unroll
        for (int mm = 0; mm < 8; ++mm)
#pragma unroll
            for (int nn = 0; nn < 2; ++nn)
#pragma unroll
                for (int rr = 0; rr < 4; ++rr) {
                    const int row = m0 + mm * 16 + qd * 4 + rr;  // token
                    const int col = n0 + nw + nn * 16 + i;       // channel
                    const float v = acc[mm][nn][rr] + bq[col];
                    const unsigned short hs = f2bf(v);
                    const float lo = v - bff(hs);
                    const int b = row >> 11, s = row & 2047;
                    const int hh = col >> 6, d = col & 63;
                    const size_t oi = ((size_t)((b << 4) + hh) * 2048 + s) * 64 + d;
                    Qb[oi] = hs;
                    Qlo[oi] = f2bf(lo);
                }
    } else {
        const int b2 = blk - 256;
        // XCD-locality remap: token-tile%8 == b2%8 (same map as Q's x-tiles)
        const int n0 = ((b2 & 7) + 8 * ((b2 >> 3) & 3)) * 128;  // token tile
        const int m0 = (b2 >> 5) * 128;                         // channel tile
        for (int k0 = 0; k0 < 1024; k0 += 64) {
            __syncthreads();
#pragma unroll
            for (int c = 0; c < 4; ++c) {
                const int r = w * 32 + c * 8;
                glds16(wvh + (size_t)(m0 + r + l8) * 1024 + k0 + gro, &Ah[r * 64]);
                glds16(xh + (size_t)(n0 + r + l8) * 1024 + k0 + gro, &Bh[r * 64]);
            }
            __syncthreads();
#pragma unroll
            for (int kc = 0; kc < 2; ++kc) {
                const int ch = (((kc * 4 + qd) ^ (i & 7)) << 3);
                short8 bf2[2];
#pragma unroll
                for (int nn = 0; nn < 2; ++nn)
                    bf2[nn] = *(const short8*)&Bh[(nw + nn * 16 + i) * 64 + ch];
#pragma unroll
                for (int mm = 0; mm < 8; ++mm) {
                    const short8 af = *(const short8*)&Ah[(mm * 16 + i) * 64 + ch];
#pragma unroll
                    for (int nn = 0; nn < 2; ++nn)
                        acc[mm][nn] = __builtin_amdgcn_mfma_f32_16x16x32_bf16(
                            af, bf2[nn], acc[mm][nn], 0, 0, 0);
                }
            }
        }
#pragma unroll
        for (int mm = 0; mm < 8; ++mm)
#pragma unroll
            for (int nn = 0; nn < 2; ++nn)
#pragma unroll
                for (int rr = 0; rr < 4; ++rr) {
                    const int rch = m0 + mm * 16 + qd * 4 + rr;  // channel
                    const int tok = n0 + nw + nn * 16 + i;       // token
                    const float v = acc[mm][nn][rr] + bv[rch];
                    const int b = tok >> 11, s = tok & 2047;
                    Vt[((size_t)(b * 1024 + rch)) * 2048 + s] = f2bf(v);
                }
    }
}

// ---------------------------------------------------------------------------
// Buckets + row norms.  q reconstructed as hi+lo from Qb/Qlo.
// ---------------------------------------------------------------------------
__global__ __launch_bounds__(256) void bucket_kernel(
    const unsigned short* __restrict__ Qb, const unsigned short* __restrict__ Qlo,
    const float* __restrict__ hp,
    int* __restrict__ buckets, float* __restrict__ rown)
{
    __shared__ float hpl[65 * 6];
    const int tid = threadIdx.x;
    if (tid < 65 * 6) hpl[tid] = hp[tid];
    __syncthreads();

    const int idx = blockIdx.x * 256 + tid;       // 65536 = 32 bh * 2048 s
    const unsigned short* qh = Qb + (size_t)idx * 64;
    const unsigned short* ql = Qlo + (size_t)idx * 64;

    float pj[6];
    float nrm = 0.f;
#pragma unroll
    for (int n = 0; n < 6; ++n) pj[n] = hpl[64 * 6 + n];
    for (int d8 = 0; d8 < 8; ++d8) {
        const short8 vh = *(const short8*)(qh + d8 * 8);
        const short8 vl = *(const short8*)(ql + d8 * 8);
#pragma unroll
        for (int e = 0; e < 8; ++e) {
            const float q = bff((unsigned short)vh[e]) + bff((unsigned short)vl[e]);
            nrm = fmaf(q, q, nrm);
#pragma unroll
            for (int n = 0; n < 6; ++n)
                pj[n] = fmaf(q, hpl[(d8 * 8 + e) * 6 + n], pj[n]);
        }
    }
    int bkt = 0;
#pragma unroll
    for (int n = 0; n < 6; ++n) bkt |= (pj[n] >= 0.f) << n;
    buckets[idx] = bkt;
    rown[idx] = nrm;
}

// ---------------------------------------------------------------------------
// Attention (EXACT verified R8 v6).  Grid (bh=32, qt=16); 4 waves; wave owns
// 32 q-rows (2 ms); K-tile 64 LDS-staged with global-side XOR swizzle.
// Fixed upper-bound softmax shift; P high-half pack.  LDS 33 KB.
// Note: grid (32,16) already gives perfect XCD locality -- all 16 qt-blocks
// of a bh land on XCD bh%8 (32%8==0), 4 bh x 768 KB = 3 MB <= 4 MB L2.
// ---------------------------------------------------------------------------
__global__ __launch_bounds__(256, 2) void attn_kernel(
    const unsigned short* __restrict__ Qb, const unsigned short* __restrict__ Qlo,
    const unsigned short* __restrict__ Vt, const int* __restrict__ bks,
    const float* __restrict__ rown, float* __restrict__ out)
{
    __shared__ unsigned short Khi[64 * 64];
    __shared__ unsigned short Klo[64 * 64];
    __shared__ unsigned short Vs[64 * 64];
    __shared__ unsigned short P[4][16 * 64];
    __shared__ float smax[4];

    const int tid = threadIdx.x;
    const int w = tid >> 6, lane = tid & 63;
    const int i = lane & 15, qd = lane >> 4;
    const int l8 = lane >> 3, j = lane & 7;
    const int bh = blockIdx.x;
    const int qbase = blockIdx.y * 128 + w * 32;

    const unsigned short* Qh = Qb + (size_t)bh * 2048 * 64;
    const unsigned short* Ql = Qlo + (size_t)bh * 2048 * 64;
    const unsigned short* Vb = Vt + (size_t)bh * 64 * 2048;
    const int* bk = bks + bh * 2048;
    const float* rnh = rown + bh * 2048;
    unsigned short* Pw = &P[w][0];

    float lm = 0.f;
    for (int t = tid; t < 2048; t += 256) lm = fmaxf(lm, rnh[t]);
#pragma unroll
    for (int msk = 1; msk < 64; msk <<= 1) lm = fmaxf(lm, __shfl_xor(lm, msk));
    if (lane == 0) smax[w] = lm;
    __syncthreads();
    const float sqM = sqrtf(fmaxf(fmaxf(smax[0], smax[1]),
                                  fmaxf(smax[2], smax[3])));

    float m2row[2][4], lrun[2][4];
    int qbr[2][4];
#pragma unroll
    for (int ms = 0; ms < 2; ++ms)
#pragma unroll
        for (int r = 0; r < 4; ++r) {
            const int row = qbase + ms * 16 + qd * 4 + r;
            m2row[ms][r] = 2.84030586f * sqrtf(rnh[row]) * sqM + 0.72134754f;
            qbr[ms][r] = bk[row];
            lrun[ms][r] = 0.f;
        }

    short8 aqh0[2], aqh1[2], aql0[2], aql1[2];
#pragma unroll
    for (int ms = 0; ms < 2; ++ms) {
        const unsigned short* qp = Qh + (size_t)(qbase + ms * 16 + i) * 64 + qd * 8;
        const unsigned short* lp = Ql + (size_t)(qbase + ms * 16 + i) * 64 + qd * 8;
        aqh0[ms] = *(const short8*)qp; aqh1[ms] = *(const short8*)(qp + 32);
        aql0[ms] = *(const short8*)lp; aql1[ms] = *(const short8*)(lp + 32);
    }

    f32x4 o[2][4];
#pragma unroll
    for (int ms = 0; ms < 2; ++ms)
#pragma unroll
        for (int d = 0; d < 4; ++d) o[ms][d] = f32x4{0.f, 0.f, 0.f, 0.f};

    for (int t0 = 0; t0 < 2048; t0 += 64) {
        __syncthreads();
#pragma unroll
        for (int c2 = 0; c2 < 2; ++c2) {
            const int r = w * 16 + c2 * 8 + l8;
            const int swz = ((j ^ l8) << 3);
            glds16(Qh + (size_t)(t0 + r) * 64 + swz, &Khi[w * 1024 + c2 * 512]);
            glds16(Ql + (size_t)(t0 + r) * 64 + swz, &Klo[w * 1024 + c2 * 512]);
            glds16(Vb + (size_t)r * 2048 + t0 + swz, &Vs[w * 1024 + c2 * 512]);
        }
        __syncthreads();

        f32x4 s[2][4];
        int kb[4];
#pragma unroll
        for (int sub = 0; sub < 4; ++sub) {
            const int kr = sub * 16 + i;
            const int sw = i & 7;
            const short8 bh0 = *(const short8*)&Khi[kr * 64 + ((qd ^ sw) << 3)];
            const short8 bh1 = *(const short8*)&Khi[kr * 64 + (((qd + 4) ^ sw) << 3)];
            const short8 bl0 = *(const short8*)&Klo[kr * 64 + ((qd ^ sw) << 3)];
            const short8 bl1 = *(const short8*)&Klo[kr * 64 + (((qd + 4) ^ sw) << 3)];
            kb[sub] = bk[t0 + kr];
#pragma unroll
            for (int ms = 0; ms < 2; ++ms) {
                f32x4 t = f32x4{0.f, 0.f, 0.f, 0.f};
                t = __builtin_amdgcn_mfma_f32_16x16x32_bf16(aqh0[ms], bh0, t, 0, 0, 0);
                t = __builtin_amdgcn_mfma_f32_16x16x32_bf16(aqh1[ms], bh1, t, 0, 0, 0);
                t = __builtin_amdgcn_mfma_f32_16x16x32_bf16(aql0[ms], bh0, t, 0, 0, 0);
                t = __builtin_amdgcn_mfma_f32_16x16x32_bf16(aql1[ms], bh1, t, 0, 0, 0);
                t = __builtin_amdgcn_mfma_f32_16x16x32_bf16(aqh0[ms], bl0, t, 0, 0, 0);
                t = __builtin_amdgcn_mfma_f32_16x16x32_bf16(aqh1[ms], bl1, t, 0, 0, 0);
                s[ms][sub] = t;
            }
        }

        short8 vb0[4], vb1[4];
#pragma unroll
        for (int dsub = 0; dsub < 4; ++dsub) {
            const int dr = dsub * 16 + i;
            const int sw = i & 7;
            vb0[dsub] = *(const short8*)&Vs[dr * 64 + ((qd ^ sw) << 3)];
            vb1[dsub] = *(const short8*)&Vs[dr * 64 + (((qd + 4) ^ sw) << 3)];
        }

#pragma unroll
        for (int ms = 0; ms < 2; ++ms) {
#pragma unroll
            for (int sub = 0; sub < 4; ++sub)
#pragma unroll
                for (int r = 0; r < 4; ++r) {
                    const float c2f = (kb[sub] == qbr[ms][r]) ? 2.84030586f
                                                              : 2.79522164f;
                    const float p = exp2f(fmaf(s[ms][sub][r], c2f, -m2row[ms][r]));
                    lrun[ms][r] += p;
                    const unsigned int pu = __float_as_uint(p);
                    const int row = qd * 4 + r, col = sub * 16 + i;
                    Pw[row * 64 + (((col >> 3) ^ (row & 7)) << 3) + (col & 7)] =
                        (unsigned short)(pu >> 16);
                }
            const short8 pa0 = *(const short8*)&Pw[i * 64 + ((qd ^ (i & 7)) << 3)];
            const short8 pa1 = *(const short8*)&Pw[i * 64 + (((qd + 4) ^ (i & 7)) << 3)];
#pragma unroll
            for (int dsub = 0; dsub < 4; ++dsub) {
                o[ms][dsub] = __builtin_amdgcn_mfma_f32_16x16x32_bf16(
                    pa0, vb0[dsub], o[ms][dsub], 0, 0, 0);
                o[ms][dsub] = __builtin_amdgcn_mfma_f32_16x16x32_bf16(
                    pa1, vb1[dsub], o[ms][dsub], 0, 0, 0);
            }
        }
    }

#pragma unroll
    for (int ms = 0; ms < 2; ++ms)
#pragma unroll
        for (int r = 0; r < 4; ++r) {
#pragma unroll
            for (int msk = 1; msk < 16; msk <<= 1)
                lrun[ms][r] += __shfl_xor(lrun[ms][r], msk);
        }
    const int b = bh >> 4, h = bh & 15;
#pragma unroll
    for (int ms = 0; ms < 2; ++ms)
#pragma unroll
        for (int dsub = 0; dsub < 4; ++dsub)
#pragma unroll
            for (int r = 0; r < 4; ++r) {
                const float v = o[ms][dsub][r] / lrun[ms][r];
                const int srow = qbase + ms * 16 + qd * 4 + r;
                out[((size_t)(b * 2048 + srow)) * 1024 + h * 64 + dsub * 16 + i] = v;
            }
}

// ---------------------------------------------------------------------------
extern "C" void kernel_launch(void* const* d_in, const int* in_sizes, int n_in,
                              void* d_out, int out_size, void* d_ws, size_t ws_size,
                              hipStream_t stream)
{
    const float* x  = (const float*)d_in[0];
    const float* Wq = (const float*)d_in[1];
    const float* bq = (const float*)d_in[2];
    const float* Wv = (const float*)d_in[3];
    const float* bv = (const float*)d_in[4];
    const float* hp = (const float*)d_in[5];
    float* out = (float*)d_out;

    char* ws = (char*)d_ws;
    const size_t MB = (size_t)1 << 20;
    unsigned short* xh  = (unsigned short*)(ws);            // 8 MB
    unsigned short* xl  = (unsigned short*)(ws + 8 * MB);   // 8 MB
    unsigned short* Wqh = (unsigned short*)(ws + 16 * MB);  // 2 MB
    unsigned short* Wql = (unsigned short*)(ws + 18 * MB);  // 2 MB
    unsigned short* Wvh = (unsigned short*)(ws + 20 * MB);  // 2 MB
    unsigned short* Qb  = (unsigned short*)(ws + 22 * MB);  // 8 MB
    unsigned short* Qlo = (unsigned short*)(ws + 30 * MB);  // 8 MB
    unsigned short* Vt  = (unsigned short*)(ws + 38 * MB);  // 8 MB
    int*        buckets = (int*)(ws + 62 * MB);             // 256 KB
    float*         rown = (float*)(ws + 62 * MB + 256 * 1024);  // 256 KB

    split_all<<<dim3(6144), 256, 0, stream>>>(x, Wq, Wv, xh, xl, Wqh, Wql, Wvh);
    gemm_qv<<<dim3(512), 256, 0, stream>>>(xh, xl, Wqh, Wql, Wvh, bq, bv,
                                           Qb, Qlo, Vt);
    bucket_kernel<<<dim3(256), 256, 0, stream>>>(Qb, Qlo, hp, buckets, rown);
    attn_kernel<<<dim3(32, 16), 256, 0, stream>>>(Qb, Qlo, Vt, buckets, rown, out);
}